// Round 8
// baseline (408.490 us; speedup 1.0000x reference)
//
#include <hip/hip_runtime.h>
#include <hip/hip_bf16.h>

#define N_NODES 65536
#define N_EDGES 524288
#define DIM 128
#define NGRAPH 64
#define OUTD 10

// ---------------------------------------------------------------------------
// CSR build: histogram -> exclusive scan (2-level) -> atomic-cursor fill
// ---------------------------------------------------------------------------
__global__ void hist_kernel(const int* __restrict__ dst, int* __restrict__ counts) {
    int e = blockIdx.x * 256 + threadIdx.x;
    if (e < N_EDGES) atomicAdd(&counts[dst[e]], 1);
}

__global__ void scanA_kernel(const int* __restrict__ counts, int* __restrict__ offs,
                             int* __restrict__ btot) {
    __shared__ int lds[1024];
    int t = threadIdx.x;
    int base = blockIdx.x * 1024;
    int v = counts[base + t];
    lds[t] = v;
    __syncthreads();
    for (int off = 1; off < 1024; off <<= 1) {
        int y = (t >= off) ? lds[t - off] : 0;
        __syncthreads();
        lds[t] += y;
        __syncthreads();
    }
    offs[base + t] = lds[t] - v;        // block-local exclusive
    if (t == 1023) btot[blockIdx.x] = lds[t];
}

__global__ void scanB_kernel(int* __restrict__ btot) {
    __shared__ int lds[64];
    int t = threadIdx.x;  // 64 threads
    int v = btot[t];
    lds[t] = v;
    __syncthreads();
    for (int off = 1; off < 64; off <<= 1) {
        int y = (t >= off) ? lds[t - off] : 0;
        __syncthreads();
        lds[t] += y;
        __syncthreads();
    }
    btot[t] = lds[t] - v;               // exclusive block offsets
}

__global__ void scanC_kernel(int* __restrict__ offs, const int* __restrict__ btot,
                             int* __restrict__ cursor) {
    int t = blockIdx.x * 1024 + threadIdx.x;
    int v = offs[t] + btot[blockIdx.x];
    offs[t] = v;
    cursor[t] = v;                      // cursor init fused (removes d2d memcpy)
    if (t == 0) offs[N_NODES] = N_EDGES;
}

__global__ void fill_kernel(const int* __restrict__ dst, const int* __restrict__ src,
                            int* __restrict__ cursor, int* __restrict__ csr_src) {
    int e = blockIdx.x * 256 + threadIdx.x;
    if (e < N_EDGES) {
        int d = dst[e];
        int pos = atomicAdd(&cursor[d], 1);
        csr_src[pos] = src[e];
    }
}

// ---------------------------------------------------------------------------
// GEMM v3: C[M,128] = H[M,128] @ W[128,128], fp32.  (unchanged from R7 —
// measured <45us/dispatch; W staged in LDS, 8x8 thread tile, 2 blocks/CU.)
// ---------------------------------------------------------------------------
__global__ __launch_bounds__(256, 2) void gemm_kernel(const float* __restrict__ H,
                                                      const float* __restrict__ W,
                                                      float* __restrict__ C) {
    __shared__ float4 Hs[128 * 16];   // H[r][c4] at [r*16 + (c4 ^ ((r>>1)&15))]
    __shared__ float4 Ws0[64 * 16];   // W[k][f4 col 2j]   at [k*16 + j]
    __shared__ float4 Ws1[64 * 16];   // W[k][f4 col 2j+1] at [k*16 + j]
    int tid = threadIdx.x;
    int row0 = blockIdx.x * 128;
    int rg = tid >> 4;                // 0..15 -> rows rg*8 .. rg*8+7
    int cg = tid & 15;                // 0..15 -> cols cg*8 .. cg*8+7

    const float4* H4 = (const float4*)H;
    const float4* W4 = (const float4*)W;
    float acc[8][8] = {};

    for (int kh = 0; kh < 2; ++kh) {
        // --- stage H half-tile: 128 rows x 16 f4 (32 KiB), coalesced ---
#pragma unroll
        for (int i = 0; i < 8; ++i) {
            int f = tid + i * 256;        // 0..2047
            int r = f >> 4, c4 = f & 15;
            Hs[r * 16 + (c4 ^ ((r >> 1) & 15))] =
                H4[(size_t)(row0 + r) * 32 + kh * 16 + c4];
        }
        // --- stage W half: 64 k-rows x 32 f4 (32 KiB), even/odd split ---
#pragma unroll
        for (int i = 0; i < 8; ++i) {
            int f = tid + i * 256;        // 0..2047
            int k = f >> 5, c4 = f & 31;
            float4 v = W4[(size_t)(kh * 64 + k) * 32 + c4];
            if (c4 & 1) Ws1[k * 16 + (c4 >> 1)] = v;
            else        Ws0[k * 16 + (c4 >> 1)] = v;
        }
        __syncthreads();

#pragma unroll 2
        for (int k0 = 0; k0 < 64; k0 += 4) {
            float4 h[8];
#pragma unroll
            for (int i = 0; i < 8; ++i) {
                int r = rg * 8 + i;
                h[i] = Hs[r * 16 + ((k0 >> 2) ^ ((r >> 1) & 15))];
            }
#pragma unroll
            for (int kk = 0; kk < 4; ++kk) {
                float4 w0 = Ws0[(k0 + kk) * 16 + cg];
                float4 w1 = Ws1[(k0 + kk) * 16 + cg];
#pragma unroll
                for (int i = 0; i < 8; ++i) {
                    float hv = (kk == 0) ? h[i].x : (kk == 1) ? h[i].y
                             : (kk == 2) ? h[i].z : h[i].w;
                    acc[i][0] += hv * w0.x; acc[i][1] += hv * w0.y;
                    acc[i][2] += hv * w0.z; acc[i][3] += hv * w0.w;
                    acc[i][4] += hv * w1.x; acc[i][5] += hv * w1.y;
                    acc[i][6] += hv * w1.z; acc[i][7] += hv * w1.w;
                }
            }
        }
        __syncthreads();
    }

#pragma unroll
    for (int i = 0; i < 8; ++i) {
        float* cp = C + (size_t)(row0 + rg * 8 + i) * DIM + cg * 8;
        *(float4*)cp       = make_float4(acc[i][0], acc[i][1], acc[i][2], acc[i][3]);
        *(float4*)(cp + 4) = make_float4(acc[i][4], acc[i][5], acc[i][6], acc[i][7]);
    }
}

// ---------------------------------------------------------------------------
// Aggregation v2 + bias + ELU: out[n] = elu( sum_{e in in(n)} t[src_e] + b )
// Two nodes per wave: each 32-lane half-wave owns one node, lane holds a
// float4 (32 lanes x 16 B = 512 B row -> ONE dwordx4 per edge-row). Halves
// gather instruction count and total waves vs R7. 4-deep ILP keeps 4 x 512 B
// in flight per half-wave (avg degree 8 -> ~2 rounds).
// ---------------------------------------------------------------------------
__global__ __launch_bounds__(256) void agg_elu_kernel(const float* __restrict__ t,
                                                      const int* __restrict__ offs,
                                                      const int* __restrict__ csr_src,
                                                      const float* __restrict__ bias,
                                                      float* __restrict__ out) {
    int wave = threadIdx.x >> 6;
    int half = (threadIdx.x >> 5) & 1;   // which half-wave
    int l32  = threadIdx.x & 31;
    int node = blockIdx.x * 8 + wave * 2 + half;
    int e0 = offs[node], e1 = offs[node + 1];
    const float4* tp = (const float4*)t;     // row = 32 float4
    float ax = 0.f, ay = 0.f, az = 0.f, aw = 0.f;
    float bx = 0.f, by = 0.f, bz = 0.f, bw = 0.f;
    int e = e0;
    for (; e + 3 < e1; e += 4) {
        int s0 = csr_src[e],     s1 = csr_src[e + 1];
        int s2 = csr_src[e + 2], s3 = csr_src[e + 3];
        float4 v0 = tp[(size_t)s0 * 32 + l32];
        float4 v1 = tp[(size_t)s1 * 32 + l32];
        float4 v2 = tp[(size_t)s2 * 32 + l32];
        float4 v3 = tp[(size_t)s3 * 32 + l32];
        ax += v0.x + v1.x; ay += v0.y + v1.y; az += v0.z + v1.z; aw += v0.w + v1.w;
        bx += v2.x + v3.x; by += v2.y + v3.y; bz += v2.z + v3.z; bw += v2.w + v3.w;
    }
    for (; e < e1; ++e) {
        int s0 = csr_src[e];
        float4 v0 = tp[(size_t)s0 * 32 + l32];
        ax += v0.x; ay += v0.y; az += v0.z; aw += v0.w;
    }
    ax += bx; ay += by; az += bz; aw += bw;
    float4 bv = ((const float4*)bias)[l32];
    float x = ax + bv.x, y = ay + bv.y, z = az + bv.z, w = aw + bv.w;
    x = x > 0.f ? x : expm1f(x);
    y = y > 0.f ? y : expm1f(y);
    z = z > 0.f ? z : expm1f(z);
    w = w > 0.f ? w : expm1f(w);
    ((float4*)out)[(size_t)node * 32 + l32] = make_float4(x, y, z, w);
}

// ---------------------------------------------------------------------------
// Per-graph mean pooling (graph_ids sorted): run-length accumulate, atomics
// only at run transitions.
// ---------------------------------------------------------------------------
__global__ __launch_bounds__(128) void pool_kernel(const float* __restrict__ h,
                                                   const int* __restrict__ gid,
                                                   float* __restrict__ sums,
                                                   int* __restrict__ gcount) {
    int c = threadIdx.x;                 // 0..127
    int n0 = blockIdx.x * 64;
    int cur = gid[n0];
    float acc = 0.f;
    int cnt = 0;
    for (int i = 0; i < 64; ++i) {
        int n = n0 + i;
        int g = gid[n];
        if (g != cur) {
            atomicAdd(&sums[cur * DIM + c], acc);
            if (c == 0) atomicAdd(&gcount[cur], cnt);
            cur = g; acc = 0.f; cnt = 0;
        }
        acc += h[(size_t)n * DIM + c];
        cnt++;
    }
    atomicAdd(&sums[cur * DIM + c], acc);
    if (c == 0) atomicAdd(&gcount[cur], cnt);
}

__global__ __launch_bounds__(128) void final_kernel(const float* __restrict__ sums,
                                                    const int* __restrict__ gcount,
                                                    const float* __restrict__ Wc,
                                                    const float* __restrict__ bc,
                                                    float* __restrict__ out) {
    __shared__ float hg[DIM];
    int g = blockIdx.x;
    int t = threadIdx.x;
    float cnt = (float)gcount[g];
    cnt = cnt > 1.f ? cnt : 1.f;
    hg[t] = sums[g * DIM + t] / cnt;
    __syncthreads();
    if (t < OUTD) {
        float a = bc[t];
        for (int d = 0; d < DIM; ++d) a += hg[d] * Wc[d * OUTD + t];
        out[g * OUTD + t] = a;
    }
}

// ---------------------------------------------------------------------------
extern "C" void kernel_launch(void* const* d_in, const int* in_sizes, int n_in,
                              void* d_out, int out_size, void* d_ws, size_t ws_size,
                              hipStream_t stream) {
    const float* features = (const float*)d_in[0];
    const int* src = (const int*)d_in[1];
    const int* dst = (const int*)d_in[2];
    const int* gid = (const int*)d_in[3];
    const float* W1 = (const float*)d_in[4];
    const float* b1 = (const float*)d_in[5];
    const float* W2 = (const float*)d_in[6];
    const float* b2 = (const float*)d_in[7];
    const float* W3 = (const float*)d_in[8];
    const float* b3 = (const float*)d_in[9];
    const float* Wc = (const float*)d_in[10];
    const float* bc = (const float*)d_in[11];
    float* out = (float*)d_out;

    // workspace carve-up
    char* ws = (char*)d_ws;
    float* tbuf   = (float*)ws;                 ws += (size_t)N_NODES * DIM * 4;   // 32 MiB
    float* hbuf   = (float*)ws;                 ws += (size_t)N_NODES * DIM * 4;   // 32 MiB
    int*   csr    = (int*)ws;                   ws += (size_t)N_EDGES * 4;
    int*   offs   = (int*)ws;                   ws += (size_t)(N_NODES + 64) * 4;
    int*   counts = (int*)ws;                   ws += (size_t)N_NODES * 4;
    int*   cursor = (int*)ws;                   ws += (size_t)N_NODES * 4;
    int*   btot   = (int*)ws;                   ws += 64 * 4;
    float* sums   = (float*)ws;                 ws += (size_t)NGRAPH * DIM * 4;
    int*   gcount = (int*)ws;                   ws += NGRAPH * 4;

    // --- CSR build ---
    hipMemsetAsync(counts, 0, (size_t)N_NODES * 4, stream);
    hist_kernel<<<N_EDGES / 256, 256, 0, stream>>>(dst, counts);
    scanA_kernel<<<64, 1024, 0, stream>>>(counts, offs, btot);
    scanB_kernel<<<1, 64, 0, stream>>>(btot);
    scanC_kernel<<<64, 1024, 0, stream>>>(offs, btot, cursor);
    fill_kernel<<<N_EDGES / 256, 256, 0, stream>>>(dst, src, cursor, csr);

    // --- 3 GCN layers: t = h @ W ; h' = elu(A @ t + b) ---
    gemm_kernel<<<N_NODES / 128, 256, 0, stream>>>(features, W1, tbuf);
    agg_elu_kernel<<<N_NODES / 8, 256, 0, stream>>>(tbuf, offs, csr, b1, hbuf);
    gemm_kernel<<<N_NODES / 128, 256, 0, stream>>>(hbuf, W2, tbuf);
    agg_elu_kernel<<<N_NODES / 8, 256, 0, stream>>>(tbuf, offs, csr, b2, hbuf);
    gemm_kernel<<<N_NODES / 128, 256, 0, stream>>>(hbuf, W3, tbuf);
    agg_elu_kernel<<<N_NODES / 8, 256, 0, stream>>>(tbuf, offs, csr, b3, hbuf);

    // --- pooling + classifier ---
    hipMemsetAsync(sums, 0, (size_t)(NGRAPH * DIM * 4 + NGRAPH * 4), stream);
    pool_kernel<<<N_NODES / 64, 128, 0, stream>>>(hbuf, gid, sums, gcount);
    final_kernel<<<NGRAPH, 128, 0, stream>>>(sums, gcount, Wc, bc, out);
}

// Round 13
// 368.310 us; speedup vs baseline: 1.1091x; 1.1091x over previous
//
#include <hip/hip_runtime.h>
#include <hip/hip_bf16.h>

#define N_NODES 65536
#define N_EDGES 524288
#define DIM 128
#define NGRAPH 64
#define OUTD 10

// bf16 helpers (manual RNE round + unpack; avoids API ambiguity)
__device__ __forceinline__ unsigned r16(float x) {
    unsigned u = __float_as_uint(x);
    return (u + 0x7FFFu + ((u >> 16) & 1u)) >> 16;
}
__device__ __forceinline__ unsigned packbf2(float a, float b) {
    return r16(a) | (r16(b) << 16);
}
__device__ __forceinline__ float bflo(unsigned u) { return __uint_as_float(u << 16); }
__device__ __forceinline__ float bfhi(unsigned u) { return __uint_as_float(u & 0xFFFF0000u); }

// ---------------------------------------------------------------------------
// CSR build: histogram -> exclusive scan (2-level) -> atomic-cursor fill
// ---------------------------------------------------------------------------
__global__ void hist_kernel(const int* __restrict__ dst, int* __restrict__ counts) {
    int e = blockIdx.x * 256 + threadIdx.x;
    if (e < N_EDGES) atomicAdd(&counts[dst[e]], 1);
}

__global__ void scanA_kernel(const int* __restrict__ counts, int* __restrict__ offs,
                             int* __restrict__ btot) {
    __shared__ int lds[1024];
    int t = threadIdx.x;
    int base = blockIdx.x * 1024;
    int v = counts[base + t];
    lds[t] = v;
    __syncthreads();
    for (int off = 1; off < 1024; off <<= 1) {
        int y = (t >= off) ? lds[t - off] : 0;
        __syncthreads();
        lds[t] += y;
        __syncthreads();
    }
    offs[base + t] = lds[t] - v;        // block-local exclusive
    if (t == 1023) btot[blockIdx.x] = lds[t];
}

__global__ void scanB_kernel(int* __restrict__ btot) {
    __shared__ int lds[64];
    int t = threadIdx.x;  // 64 threads
    int v = btot[t];
    lds[t] = v;
    __syncthreads();
    for (int off = 1; off < 64; off <<= 1) {
        int y = (t >= off) ? lds[t - off] : 0;
        __syncthreads();
        lds[t] += y;
        __syncthreads();
    }
    btot[t] = lds[t] - v;               // exclusive block offsets
}

__global__ void scanC_kernel(int* __restrict__ offs, const int* __restrict__ btot,
                             int* __restrict__ cursor) {
    int t = blockIdx.x * 1024 + threadIdx.x;
    int v = offs[t] + btot[blockIdx.x];
    offs[t] = v;
    cursor[t] = v;                      // cursor init fused (removes d2d memcpy)
    if (t == 0) offs[N_NODES] = N_EDGES;
}

__global__ void fill_kernel(const int* __restrict__ dst, const int* __restrict__ src,
                            int* __restrict__ cursor, int* __restrict__ csr_src) {
    int e = blockIdx.x * 256 + threadIdx.x;
    if (e < N_EDGES) {
        int d = dst[e];
        int pos = atomicAdd(&cursor[d], 1);
        csr_src[pos] = src[e];
    }
}

// ---------------------------------------------------------------------------
// GEMM v4: T[M,128](bf16) = H[M,128](fp32) @ W[128,128](fp32), fp32 math.
// Same structure as measured v3 (~44us); only the C-write converts to bf16
// (RNE) and packs 8 cols into one uint4 store -> WRITE_SIZE halves.
// ---------------------------------------------------------------------------
__global__ __launch_bounds__(256, 2) void gemm_kernel(const float* __restrict__ H,
                                                      const float* __restrict__ W,
                                                      unsigned* __restrict__ T) {
    __shared__ float4 Hs[128 * 16];   // H[r][c4] at [r*16 + (c4 ^ ((r>>1)&15))]
    __shared__ float4 Ws0[64 * 16];   // W[k][f4 col 2j]   at [k*16 + j]
    __shared__ float4 Ws1[64 * 16];   // W[k][f4 col 2j+1] at [k*16 + j]
    int tid = threadIdx.x;
    int row0 = blockIdx.x * 128;
    int rg = tid >> 4;                // 0..15 -> rows rg*8 .. rg*8+7
    int cg = tid & 15;                // 0..15 -> cols cg*8 .. cg*8+7

    const float4* H4 = (const float4*)H;
    const float4* W4 = (const float4*)W;
    float acc[8][8] = {};

    for (int kh = 0; kh < 2; ++kh) {
        // --- stage H half-tile: 128 rows x 16 f4 (32 KiB), coalesced ---
#pragma unroll
        for (int i = 0; i < 8; ++i) {
            int f = tid + i * 256;        // 0..2047
            int r = f >> 4, c4 = f & 15;
            Hs[r * 16 + (c4 ^ ((r >> 1) & 15))] =
                H4[(size_t)(row0 + r) * 32 + kh * 16 + c4];
        }
        // --- stage W half: 64 k-rows x 32 f4 (32 KiB), even/odd split ---
#pragma unroll
        for (int i = 0; i < 8; ++i) {
            int f = tid + i * 256;        // 0..2047
            int k = f >> 5, c4 = f & 31;
            float4 v = W4[(size_t)(kh * 64 + k) * 32 + c4];
            if (c4 & 1) Ws1[k * 16 + (c4 >> 1)] = v;
            else        Ws0[k * 16 + (c4 >> 1)] = v;
        }
        __syncthreads();

#pragma unroll 2
        for (int k0 = 0; k0 < 64; k0 += 4) {
            float4 h[8];
#pragma unroll
            for (int i = 0; i < 8; ++i) {
                int r = rg * 8 + i;
                h[i] = Hs[r * 16 + ((k0 >> 2) ^ ((r >> 1) & 15))];
            }
#pragma unroll
            for (int kk = 0; kk < 4; ++kk) {
                float4 w0 = Ws0[(k0 + kk) * 16 + cg];
                float4 w1 = Ws1[(k0 + kk) * 16 + cg];
#pragma unroll
                for (int i = 0; i < 8; ++i) {
                    float hv = (kk == 0) ? h[i].x : (kk == 1) ? h[i].y
                             : (kk == 2) ? h[i].z : h[i].w;
                    acc[i][0] += hv * w0.x; acc[i][1] += hv * w0.y;
                    acc[i][2] += hv * w0.z; acc[i][3] += hv * w0.w;
                    acc[i][4] += hv * w1.x; acc[i][5] += hv * w1.y;
                    acc[i][6] += hv * w1.z; acc[i][7] += hv * w1.w;
                }
            }
        }
        __syncthreads();
    }

    uint4* T4 = (uint4*)T;               // row pitch = 16 uint4 (128 bf16)
#pragma unroll
    for (int i = 0; i < 8; ++i) {
        uint4 o;
        o.x = packbf2(acc[i][0], acc[i][1]);
        o.y = packbf2(acc[i][2], acc[i][3]);
        o.z = packbf2(acc[i][4], acc[i][5]);
        o.w = packbf2(acc[i][6], acc[i][7]);
        T4[(size_t)(row0 + rg * 8 + i) * 16 + cg] = o;
    }
}

// ---------------------------------------------------------------------------
// Aggregation v3 (bf16 gather) + bias + ELU:
//   out[n] = elu( sum_{e in in(n)} bf16row(t[src_e]) + b )   [fp32 accum]
// Two nodes per wave; 32-lane half-wave per node; lane = 4 cols as uint2
// (8 B x 32 lanes = 256 B row -> one dwordx2 per edge-row). Halves both
// logical gather traffic and L2-miss traffic vs fp32 rows.
// ---------------------------------------------------------------------------
__global__ __launch_bounds__(256) void agg_elu_kernel(const unsigned* __restrict__ t,
                                                      const int* __restrict__ offs,
                                                      const int* __restrict__ csr_src,
                                                      const float* __restrict__ bias,
                                                      float* __restrict__ out) {
    int wave = threadIdx.x >> 6;
    int half = (threadIdx.x >> 5) & 1;
    int l32  = threadIdx.x & 31;
    int node = blockIdx.x * 8 + wave * 2 + half;
    int e0 = offs[node], e1 = offs[node + 1];
    const uint2* tp = (const uint2*)t;       // row = 32 uint2 (256 B)
    float ax = 0.f, ay = 0.f, az = 0.f, aw = 0.f;
    float bx = 0.f, by = 0.f, bz = 0.f, bw = 0.f;
    int e = e0;
    for (; e + 3 < e1; e += 4) {
        int s0 = csr_src[e],     s1 = csr_src[e + 1];
        int s2 = csr_src[e + 2], s3 = csr_src[e + 3];
        uint2 v0 = tp[(size_t)s0 * 32 + l32];
        uint2 v1 = tp[(size_t)s1 * 32 + l32];
        uint2 v2 = tp[(size_t)s2 * 32 + l32];
        uint2 v3 = tp[(size_t)s3 * 32 + l32];
        ax += bflo(v0.x) + bflo(v1.x); ay += bfhi(v0.x) + bfhi(v1.x);
        az += bflo(v0.y) + bflo(v1.y); aw += bfhi(v0.y) + bfhi(v1.y);
        bx += bflo(v2.x) + bflo(v3.x); by += bfhi(v2.x) + bfhi(v3.x);
        bz += bflo(v2.y) + bflo(v3.y); bw += bfhi(v2.y) + bfhi(v3.y);
    }
    for (; e < e1; ++e) {
        int s0 = csr_src[e];
        uint2 v0 = tp[(size_t)s0 * 32 + l32];
        ax += bflo(v0.x); ay += bfhi(v0.x);
        az += bflo(v0.y); aw += bfhi(v0.y);
    }
    ax += bx; ay += by; az += bz; aw += bw;
    float4 bv = ((const float4*)bias)[l32];
    float x = ax + bv.x, y = ay + bv.y, z = az + bv.z, w = aw + bv.w;
    x = x > 0.f ? x : expm1f(x);
    y = y > 0.f ? y : expm1f(y);
    z = z > 0.f ? z : expm1f(z);
    w = w > 0.f ? w : expm1f(w);
    ((float4*)out)[(size_t)node * 32 + l32] = make_float4(x, y, z, w);
}

// ---------------------------------------------------------------------------
// Per-graph mean pooling (graph_ids sorted): run-length accumulate, atomics
// only at run transitions.
// ---------------------------------------------------------------------------
__global__ __launch_bounds__(128) void pool_kernel(const float* __restrict__ h,
                                                   const int* __restrict__ gid,
                                                   float* __restrict__ sums,
                                                   int* __restrict__ gcount) {
    int c = threadIdx.x;                 // 0..127
    int n0 = blockIdx.x * 64;
    int cur = gid[n0];
    float acc = 0.f;
    int cnt = 0;
    for (int i = 0; i < 64; ++i) {
        int n = n0 + i;
        int g = gid[n];
        if (g != cur) {
            atomicAdd(&sums[cur * DIM + c], acc);
            if (c == 0) atomicAdd(&gcount[cur], cnt);
            cur = g; acc = 0.f; cnt = 0;
        }
        acc += h[(size_t)n * DIM + c];
        cnt++;
    }
    atomicAdd(&sums[cur * DIM + c], acc);
    if (c == 0) atomicAdd(&gcount[cur], cnt);
}

__global__ __launch_bounds__(128) void final_kernel(const float* __restrict__ sums,
                                                    const int* __restrict__ gcount,
                                                    const float* __restrict__ Wc,
                                                    const float* __restrict__ bc,
                                                    float* __restrict__ out) {
    __shared__ float hg[DIM];
    int g = blockIdx.x;
    int t = threadIdx.x;
    float cnt = (float)gcount[g];
    cnt = cnt > 1.f ? cnt : 1.f;
    hg[t] = sums[g * DIM + t] / cnt;
    __syncthreads();
    if (t < OUTD) {
        float a = bc[t];
        for (int d = 0; d < DIM; ++d) a += hg[d] * Wc[d * OUTD + t];
        out[g * OUTD + t] = a;
    }
}

// ---------------------------------------------------------------------------
extern "C" void kernel_launch(void* const* d_in, const int* in_sizes, int n_in,
                              void* d_out, int out_size, void* d_ws, size_t ws_size,
                              hipStream_t stream) {
    const float* features = (const float*)d_in[0];
    const int* src = (const int*)d_in[1];
    const int* dst = (const int*)d_in[2];
    const int* gid = (const int*)d_in[3];
    const float* W1 = (const float*)d_in[4];
    const float* b1 = (const float*)d_in[5];
    const float* W2 = (const float*)d_in[6];
    const float* b2 = (const float*)d_in[7];
    const float* W3 = (const float*)d_in[8];
    const float* b3 = (const float*)d_in[9];
    const float* Wc = (const float*)d_in[10];
    const float* bc = (const float*)d_in[11];
    float* out = (float*)d_out;

    // workspace carve-up
    char* ws = (char*)d_ws;
    unsigned* tbuf = (unsigned*)ws;             ws += (size_t)N_NODES * DIM * 2;   // 16 MiB (bf16)
    float* hbuf   = (float*)ws;                 ws += (size_t)N_NODES * DIM * 4;   // 32 MiB
    int*   csr    = (int*)ws;                   ws += (size_t)N_EDGES * 4;
    int*   offs   = (int*)ws;                   ws += (size_t)(N_NODES + 64) * 4;
    int*   counts = (int*)ws;                   ws += (size_t)N_NODES * 4;
    int*   cursor = (int*)ws;                   ws += (size_t)N_NODES * 4;
    int*   btot   = (int*)ws;                   ws += 64 * 4;
    float* sums   = (float*)ws;                 ws += (size_t)NGRAPH * DIM * 4;
    int*   gcount = (int*)ws;                   ws += NGRAPH * 4;

    // --- CSR build ---
    hipMemsetAsync(counts, 0, (size_t)N_NODES * 4, stream);
    hist_kernel<<<N_EDGES / 256, 256, 0, stream>>>(dst, counts);
    scanA_kernel<<<64, 1024, 0, stream>>>(counts, offs, btot);
    scanB_kernel<<<1, 64, 0, stream>>>(btot);
    scanC_kernel<<<64, 1024, 0, stream>>>(offs, btot, cursor);
    fill_kernel<<<N_EDGES / 256, 256, 0, stream>>>(dst, src, cursor, csr);

    // --- 3 GCN layers: t = bf16(h @ W) ; h' = elu(A @ t + b) ---
    gemm_kernel<<<N_NODES / 128, 256, 0, stream>>>(features, W1, tbuf);
    agg_elu_kernel<<<N_NODES / 8, 256, 0, stream>>>(tbuf, offs, csr, b1, hbuf);
    gemm_kernel<<<N_NODES / 128, 256, 0, stream>>>(hbuf, W2, tbuf);
    agg_elu_kernel<<<N_NODES / 8, 256, 0, stream>>>(tbuf, offs, csr, b2, hbuf);
    gemm_kernel<<<N_NODES / 128, 256, 0, stream>>>(hbuf, W3, tbuf);
    agg_elu_kernel<<<N_NODES / 8, 256, 0, stream>>>(tbuf, offs, csr, b3, hbuf);

    // --- pooling + classifier ---
    hipMemsetAsync(sums, 0, (size_t)(NGRAPH * DIM * 4 + NGRAPH * 4), stream);
    pool_kernel<<<N_NODES / 64, 128, 0, stream>>>(hbuf, gid, sums, gcount);
    final_kernel<<<NGRAPH, 128, 0, stream>>>(sums, gcount, Wc, bc, out);
}